// Round 12
// baseline (117.784 us; speedup 1.0000x reference)
//
#include <hip/hip_runtime.h>
#include <hip/hip_bf16.h>

// GridAttention: B=2, C=64, H=W=160, INTERVAL=8, HEADS=4, d=16
// Bp=128, h=w=20, N=400 (padded to 416). Token-major [bp][n][c], c=head*16+dd.

#define N_TOK 400
#define NP    416
#define BP    128

typedef short bf16x8 __attribute__((ext_vector_type(8)));
typedef float f32x16 __attribute__((ext_vector_type(16)));

__device__ inline ushort f2bf(float f) {
    __hip_bfloat16 h = __float2bfloat16(f);
    return *reinterpret_cast<ushort*>(&h);
}
__device__ inline float bf2f(ushort u) {
    union { uint i; float f; } v; v.i = (uint)u << 16; return v.f;
}
__device__ inline uint pk2(float a, float b) {
    return (uint)f2bf(a) | ((uint)f2bf(b) << 16);
}
__device__ inline bf16x8 ld16(const ushort* p) {
    union { uint4 q; bf16x8 v; } u;
    u.q = *reinterpret_cast<const uint4*>(p);
    return u.v;
}
__device__ inline float fast_exp2(float x) {
#if __has_builtin(__builtin_amdgcn_exp2f)
    return __builtin_amdgcn_exp2f(x);
#else
    return __expf(x * 0.6931471805599453f);
#endif
}
__device__ inline float fast_rcp(float x) {
#if __has_builtin(__builtin_amdgcn_rcpf)
    return __builtin_amdgcn_rcpf(x);
#else
    return 1.0f / x;
#endif
}

#define L2E 1.4426950408889634f
#define QK_PRESCALE 0.36067376022224085f   // 0.25 * log2(e), folded into Qb/Kb at conv

// ---------------- K0: fused weight prep + bias MLP ----------------
// blocks [0,2704): biasF[h][qt][mt][lane][r] fp32, value = log2(e)*bias (fragment-major,
//   n = qt*32+(lane&31), m = mt*32+(r&3)+8*(r>>2)+4*(lane>>5)); 692224 floats.
// blocks [2704,2801): bf16 weight conversion + bias concat.
__global__ __launch_bounds__(256) void k_prep(
    const float* __restrict__ W1, const float* __restrict__ B1,
    const float* __restrict__ W2, const float* __restrict__ B2,
    const float* __restrict__ qkv_w, const float* __restrict__ qkv_b,
    const float* __restrict__ grid_w, const float* __restrict__ grid_b,
    const float* __restrict__ p1w, const float* __restrict__ p2w,
    float* __restrict__ biasF, ushort* __restrict__ Wc, float* __restrict__ Bc,
    ushort* __restrict__ Wp1, ushort* __restrict__ Wp2)
{
    int blk = blockIdx.x;
    if (blk < 2704) {
        int idx = blk * 256 + threadIdx.x;
        if (idx >= 692224) return;
        int r = idx & 15, lane = (idx >> 4) & 63;
        int tile = idx >> 10;
        int mt = tile % 13, rem = tile / 13, qt = rem % 13, h = rem / 13;
        int n = qt * 32 + (lane & 31);
        int m = mt * 32 + (r & 3) + 8 * (r >> 2) + 4 * (lane >> 5);
        float val = 0.0f;
        if (n < 400 && m < 400) {
            float r0 = (float)(n / 20 - m / 20) * (1.0f / 19.0f);
            float r1 = (float)(n % 20 - m % 20) * (1.0f / 19.0f);
            float o = B2[h];
#pragma unroll
            for (int k = 0; k < 16; ++k) {
                float hh = r0 * W1[k] + r1 * W1[16 + k] + B1[k];
                hh = fmaxf(hh, 0.0f);
                o += hh * W2[k * 4 + h];
            }
            val = o * L2E;   // exp2 domain; QK scale carried by Qb/Kb prescale
        }
        biasF[idx] = val;
    } else {
        int t = (blk - 2704) * 256 + threadIdx.x;
        if (t < 16384) {
            int oc = t >> 6, k = t & 63;
            float v = (oc < 192) ? qkv_w[oc * 64 + k] : grid_w[(oc - 192) * 64 + k];
            Wc[t] = f2bf(v);
        } else if (t < 16384 + 4096) {
            Wp1[t - 16384] = f2bf(p1w[t - 16384]);
        } else if (t < 16384 + 8192) {
            Wp2[t - 16384 - 4096] = f2bf(p2w[t - 16384 - 4096]);
        } else if (t < 16384 + 8192 + 256) {
            int oc = t - 16384 - 8192;
            Bc[oc] = (oc < 192) ? qkv_b[oc] : grid_b[oc - 192];
        }
    }
}

// ---------------- K2: fused qkv+grid conv1x1 as MFMA GEMM, shuffle on write ----------------
// Wave 0 -> Qb, 1 -> Kb (both pre-scaled by 0.25*log2e), 2 -> Vb, 3 -> XGb.
__global__ __launch_bounds__(256) void k_conv(
    const float* __restrict__ x, const ushort* __restrict__ Wc,
    const float* __restrict__ Bc,
    ushort* __restrict__ Qb, ushort* __restrict__ Kb,
    ushort* __restrict__ Vb, ushort* __restrict__ XGb)
{
    __shared__ __align__(16) ushort XL[32 * 64];
    int blk = blockIdx.x;                 // 1600 = 2*160*5
    int b = blk / 800, rem = blk % 800;
    int H0 = rem / 5, wt = rem % 5;
    int w0 = wt * 32;
    int tid = threadIdx.x;

    {
        int c = tid >> 2, q4 = tid & 3;
        const float* xr = x + ((size_t)(b * 64 + c) * 160 + H0) * 160 + w0 + q4 * 8;
        float4 f0 = *reinterpret_cast<const float4*>(xr);
        float4 f1 = *reinterpret_cast<const float4*>(xr + 4);
        char* base = reinterpret_cast<char*>(XL);
#pragma unroll
        for (int k = 0; k < 8; ++k) {
            float v = (k < 4) ? ((const float*)&f0)[k] : ((const float*)&f1)[k - 4];
            int p = q4 * 8 + k;
            int byt = p * 128 + ((2 * c) ^ ((p & 7) << 4));
            *reinterpret_cast<ushort*>(base + byt) = f2bf(v);
        }
    }

    int lane = tid & 63, w = tid >> 6;
    int l31 = lane & 31, hi = lane >> 5;

    bf16x8 wf[2][4];
#pragma unroll
    for (int nt = 0; nt < 2; ++nt)
#pragma unroll
        for (int kk = 0; kk < 4; ++kk)
            wf[nt][kk] = ld16(&Wc[(size_t)(w * 64 + nt * 32 + l31) * 64 + kk * 16 + hi * 8]);
    __syncthreads();

    f32x16 acc0 = 0.0f, acc1 = 0.0f;
    const char* base = reinterpret_cast<const char*>(XL);
#pragma unroll
    for (int kk = 0; kk < 4; ++kk) {
        int byt = l31 * 128 + (((kk * 32 + hi * 16)) ^ ((l31 & 7) << 4));
        bf16x8 xf;
        {
            union { uint4 q; bf16x8 v; } u;
            u.q = *reinterpret_cast<const uint4*>(base + byt);
            xf = u.v;
        }
        acc0 = __builtin_amdgcn_mfma_f32_32x32x16_bf16(wf[0][kk], xf, acc0, 0, 0, 0);
        acc1 = __builtin_amdgcn_mfma_f32_32x32x16_bf16(wf[1][kk], xf, acc1, 0, 0, 0);
    }

    int W0 = w0 + l31, ww = W0 >> 3, j = W0 & 7;
    int bp = b * 64 + (H0 & 7) * 8 + j;
    int n  = (H0 >> 3) * 20 + ww;
    ushort* outb = (w == 0) ? Qb : (w == 1) ? Kb : (w == 2) ? Vb : XGb;
    float mul = (w <= 1) ? QK_PRESCALE : 1.0f;
    ushort* dst = outb + ((size_t)bp * NP + n) * 64;
#pragma unroll
    for (int nt = 0; nt < 2; ++nt) {
        const f32x16& a = nt ? acc1 : acc0;
#pragma unroll
        for (int g = 0; g < 4; ++g) {
            int cc = nt * 32 + 8 * g + 4 * hi;
            int oc = w * 64 + cc;
            uint2 uu;
            uu.x = pk2((a[4 * g + 0] + Bc[oc + 0]) * mul, (a[4 * g + 1] + Bc[oc + 1]) * mul);
            uu.y = pk2((a[4 * g + 2] + Bc[oc + 2]) * mul, (a[4 * g + 3] + Bc[oc + 3]) * mul);
            *reinterpret_cast<uint2*>(dst + cc) = uu;
        }
    }
}

// ---------------- K3: MFMA attention (13 waves, one chain per wave) ----------------
// Grid 512 = (bp, head); 832 threads = 13 waves, wave w owns qt = w exactly.
// Bias via MFMA C-operand, fragment-major f32x16 loads, double-buffer prefetched.
// Vt rows 16..31 pre-filled with bf16 1.0 -> unconditional PV B-load; cols >=16 of
// acc accumulate the softmax denominator for free.
__global__ __launch_bounds__(832) void k_attn_mfma(
    const ushort* __restrict__ Qg, const ushort* __restrict__ Kg,
    const ushort* __restrict__ Vg, const float* __restrict__ biasF,
    ushort* __restrict__ O)
{
    __shared__ ushort Ks[NP * 16];    // [m][d]
    __shared__ ushort Vt[32 * 424];   // [d][m]; rows 16..31 = bf16 1.0
    int blk = blockIdx.x;
    int bp = blk >> 2, h = blk & 3;
    int tid = threadIdx.x;

    // K: exactly 832 uint4 stores (NP rows x 2 halves)
    {
        int row = tid >> 1, half = tid & 1;
        const ushort* Ksrc = Kg + (size_t)bp * NP * 64 + h * 16;
        *reinterpret_cast<uint4*>(&Ks[row * 16 + half * 8]) =
            *reinterpret_cast<const uint4*>(&Ksrc[(size_t)row * 64 + half * 8]);
    }
    // V transpose: 800 uint4 loads scattered to columns
    if (tid < 800) {
        const ushort* Vsrc = Vg + (size_t)bp * NP * 64 + h * 16;
        int row = tid >> 1, hf = tid & 1;
        uint4 v = *reinterpret_cast<const uint4*>(&Vsrc[(size_t)row * 64 + hf * 8]);
        const ushort* pv = reinterpret_cast<const ushort*>(&v);
#pragma unroll
        for (int k = 0; k < 8; ++k)
            Vt[(hf * 8 + k) * 424 + row] = pv[k];
    }
    // ones rows 16..31 (212 uints per row, 3392 total)
    for (int j = tid; j < 3392; j += 832) {
        int row = 16 + j / 212, col2 = j % 212;
        *reinterpret_cast<uint*>(&Vt[row * 424 + col2 * 2]) = 0x3F803F80u;
    }
    __syncthreads();

    int lane = tid & 63, w = tid >> 6;   // w in 0..12
    int l31 = lane & 31, hi = lane >> 5;

    int qt = w;
    int qbase = qt * 32;
    bf16x8 qf = ld16(&Qg[((size_t)bp * NP + qbase + l31) * 64 + h * 16 + hi * 8]);
    f32x16 acc = 0.0f;
    const f32x16* bfr = reinterpret_cast<const f32x16*>(
        biasF + ((size_t)(h * 169 + qt * 13)) * 1024 + lane * 16);

    f32x16 cb = bfr[0];

#pragma unroll
    for (int mt = 0; mt < 13; ++mt) {
        const int mbase = mt * 32;
        f32x16 nb;
        if (mt < 12) nb = bfr[mt + 1];   // prefetch next tile's bias (prio 0)

        __builtin_amdgcn_s_setprio(1);
        bf16x8 kf = ld16(&Ks[(mbase + l31) * 16 + hi * 8]);
        f32x16 sv = __builtin_amdgcn_mfma_f32_32x32x16_bf16(kf, qf, cb, 0, 0, 0);

        const int nv = (mt == 12) ? 8 : 16;
        float p[16];
#pragma unroll
        for (int r = 0; r < 16; ++r)
            if (r < nv) p[r] = fast_exp2(sv[r]);

        // B-operand rows: Vt rows <16 = V^T, rows >=16 = 1.0 (denominator columns)
        {
            uint c4 = pk2(p[0], p[1]), c5 = pk2(p[2], p[3]);
            uint c6 = pk2(p[4], p[5]), c7 = pk2(p[6], p[7]);
            asm("v_permlane32_swap_b32 %0, %1" : "+v"(c4), "+v"(c6));
            asm("v_permlane32_swap_b32 %0, %1" : "+v"(c5), "+v"(c7));
            union { uint u[4]; bf16x8 v; } A;
            A.u[0] = c4; A.u[1] = c5; A.u[2] = c6; A.u[3] = c7;
            bf16x8 vf = ld16(&Vt[l31 * 424 + mbase + hi * 8]);
            acc = __builtin_amdgcn_mfma_f32_32x32x16_bf16(A.v, vf, acc, 0, 0, 0);
        }
        if (mt < 12) {
            uint c4 = pk2(p[8], p[9]),  c5 = pk2(p[10], p[11]);
            uint c6 = pk2(p[12], p[13]), c7 = pk2(p[14], p[15]);
            asm("v_permlane32_swap_b32 %0, %1" : "+v"(c4), "+v"(c6));
            asm("v_permlane32_swap_b32 %0, %1" : "+v"(c5), "+v"(c7));
            union { uint u[4]; bf16x8 v; } A;
            A.u[0] = c4; A.u[1] = c5; A.u[2] = c6; A.u[3] = c7;
            bf16x8 vf = ld16(&Vt[l31 * 424 + mbase + 16 + hi * 8]);
            acc = __builtin_amdgcn_mfma_f32_32x32x16_bf16(A.v, vf, acc, 0, 0, 0);
        }
        __builtin_amdgcn_s_setprio(0);
        cb = nb;
    }

    // normalize + store: denominator for row r sits in lane (lane|16), same register.
#pragma unroll
    for (int r = 0; r < 16; ++r) {
        int moff = (r & 3) + 8 * (r >> 2) + 4 * hi;
        int q = qbase + moff;
        float s = __shfl(acc[r], lane | 16);
        if (l31 < 16 && q < N_TOK)
            O[((size_t)bp * 400 + q) * 64 + h * 16 + l31] = f2bf(acc[r] * fast_rcp(s));
    }
}

// ---------------- K4: 64x64 proj as MFMA GEMM (bf16 in, bf16 out) ----------------
// MODE 0: out NP-padded token-major (for attn V input). MODE 1: out contiguous token-major.
template<int MODE>
__global__ __launch_bounds__(256) void k_proj(
    const ushort* __restrict__ In, const ushort* __restrict__ Wp,
    const float* __restrict__ Bv, ushort* __restrict__ Out)
{
    __shared__ __align__(16) ushort XL[128 * 64];
    size_t t0 = (size_t)blockIdx.x * 128;
    int tid = threadIdx.x;

    char* basec = reinterpret_cast<char*>(XL);
#pragma unroll
    for (int it = 0; it < 4; ++it) {
        int idx = tid + it * 256;
        int p = idx >> 3, c8 = idx & 7;
        uint4 v = *reinterpret_cast<const uint4*>(In + (t0 + p) * 64 + c8 * 8);
        int byt = p * 128 + ((c8 * 16) ^ ((p & 7) << 4));
        *reinterpret_cast<uint4*>(basec + byt) = v;
    }

    int lane = tid & 63, w = tid >> 6;
    int l31 = lane & 31, hi = lane >> 5;

    bf16x8 wf[2][4];
#pragma unroll
    for (int nt = 0; nt < 2; ++nt)
#pragma unroll
        for (int kk = 0; kk < 4; ++kk)
            wf[nt][kk] = ld16(&Wp[(size_t)(nt * 32 + l31) * 64 + kk * 16 + hi * 8]);
    __syncthreads();

    int prow = w * 32 + l31;
    f32x16 acc0 = 0.0f, acc1 = 0.0f;
#pragma unroll
    for (int kk = 0; kk < 4; ++kk) {
        int byt = prow * 128 + (((kk * 32 + hi * 16)) ^ ((prow & 7) << 4));
        union { uint4 q; bf16x8 v; } u;
        u.q = *reinterpret_cast<const uint4*>(basec + byt);
        acc0 = __builtin_amdgcn_mfma_f32_32x32x16_bf16(wf[0][kk], u.v, acc0, 0, 0, 0);
        acc1 = __builtin_amdgcn_mfma_f32_32x32x16_bf16(wf[1][kk], u.v, acc1, 0, 0, 0);
    }

    size_t t = t0 + prow;
    ushort* dst;
    if (MODE == 0) {
        int bp = (int)(t / 400), n = (int)(t % 400);
        dst = Out + ((size_t)bp * NP + n) * 64;
    } else {
        dst = Out + t * 64;
    }
#pragma unroll
    for (int nt = 0; nt < 2; ++nt) {
        const f32x16& a = nt ? acc1 : acc0;
#pragma unroll
        for (int g = 0; g < 4; ++g) {
            int cc = nt * 32 + 8 * g + 4 * hi;
            uint2 uu;
            uu.x = pk2(a[4 * g + 0] + Bv[cc + 0], a[4 * g + 1] + Bv[cc + 1]);
            uu.y = pk2(a[4 * g + 2] + Bv[cc + 2], a[4 * g + 3] + Bv[cc + 3]);
            *reinterpret_cast<uint2*>(dst + cc) = uu;
        }
    }
}

// ---------------- K5: grid_unshuffle (token-major bf16 -> [B][C][160][160] fp32) ----------------
__global__ __launch_bounds__(256) void k_unshuffle(
    const ushort* __restrict__ In, float* __restrict__ out)
{
    __shared__ __align__(16) ushort il[160 * 64];
    int blk = blockIdx.x;
    int b = blk / 160, rem = blk % 160, iI = rem / 20, hh = rem % 20;
    int tid = threadIdx.x;

    for (int idx = tid; idx < 1280; idx += 256) {
        int j = idx / 160, r2 = idx % 160, ww = r2 / 8, c8 = r2 % 8;
        int bp = b * 64 + iI * 8 + j;
        int n  = hh * 20 + ww;
        uint4 v = reinterpret_cast<const uint4*>(In + ((size_t)bp * 400 + n) * 64)[c8];
        reinterpret_cast<uint4*>(&il[(ww * 8 + j) * 64])[c8] = v;
    }
    __syncthreads();

    int c = tid >> 2, q = tid & 3;
    int H0 = hh * 8 + iI;
    float* og = out + ((size_t)(b * 64 + c) * 160 + H0) * 160;
#pragma unroll
    for (int k = 0; k < 10; ++k) {
        int f = q + 4 * k;
        float4 v;
        v.x = bf2f(il[(4 * f + 0) * 64 + c]);
        v.y = bf2f(il[(4 * f + 1) * 64 + c]);
        v.z = bf2f(il[(4 * f + 2) * 64 + c]);
        v.w = bf2f(il[(4 * f + 3) * 64 + c]);
        reinterpret_cast<float4*>(og)[f] = v;
    }
}

extern "C" void kernel_launch(void* const* d_in, const int* in_sizes, int n_in,
                              void* d_out, int out_size, void* d_ws, size_t ws_size,
                              hipStream_t stream)
{
    const float* x      = (const float*)d_in[0];
    const float* qkv_w  = (const float*)d_in[1];
    const float* qkv_b  = (const float*)d_in[2];
    const float* grid_w = (const float*)d_in[3];
    const float* grid_b = (const float*)d_in[4];
    const float* pw1    = (const float*)d_in[5];
    const float* pb1    = (const float*)d_in[6];
    const float* pw2    = (const float*)d_in[7];
    const float* pb2    = (const float*)d_in[8];
    const float* p1w    = (const float*)d_in[9];
    const float* p1b    = (const float*)d_in[10];
    const float* p2w    = (const float*)d_in[11];
    const float* p2b    = (const float*)d_in[12];

    // workspace layout (byte offsets, all 16B-aligned)
    char* W = (char*)d_ws;
    float*  biasF = (float*)(W + 0);             // 692224*4 = 2,768,896
    ushort* Wc    = (ushort*)(W + 2768896);      // 32,768
    ushort* Wp1   = (ushort*)(W + 2801664);      //  8,192
    ushort* Wp2   = (ushort*)(W + 2809856);      //  8,192
    float*  Bc    = (float*) (W + 2818048);      //  1,024
    const size_t BASE2 = 2819072;
    const size_t BB = (size_t)BP * NP * 64 * 2;  // 6,815,744 per bf16 NP buffer
    ushort* Qb = (ushort*)(W + BASE2);
    ushort* Kb = (ushort*)(W + BASE2 + 1 * BB);
    ushort* Vb = (ushort*)(W + BASE2 + 2 * BB);
    ushort* XG = (ushort*)(W + BASE2 + 3 * BB);
    ushort* P1 = (ushort*)(W + BASE2 + 4 * BB);
    const size_t OB = (size_t)BP * 400 * 64 * 2; // 6,553,600 per bf16 contiguous buffer
    ushort* O1 = (ushort*)(W + BASE2 + 5 * BB);
    ushort* O2 = (ushort*)(W + BASE2 + 5 * BB + OB);
    ushort* OFb = O1;   // proj2 output reuses O1 (dead after proj1)
    float*  out = (float*)d_out;

    k_prep<<<2801, 256, 0, stream>>>(pw1, pb1, pw2, pb2, qkv_w, qkv_b, grid_w, grid_b,
                                     p1w, p2w, biasF, Wc, Bc, Wp1, Wp2);
    k_conv<<<1600, 256, 0, stream>>>(x, Wc, Bc, Qb, Kb, Vb, XG);
    // attn1: q=XG, k=Kb(prescaled), v=Vb -> O1; proj1 -> P1 (bf16, NP-padded)
    k_attn_mfma<<<512, 832, 0, stream>>>(XG, Kb, Vb, biasF, O1);
    k_proj<0><<<400, 256, 0, stream>>>(O1, Wp1, p1b, P1);
    // attn2: q=Qb(prescaled), k=XG, v=P1 -> O2; proj2 -> OFb (bf16, overlays O1)
    k_attn_mfma<<<512, 832, 0, stream>>>(Qb, XG, P1, biasF, O2);
    k_proj<1><<<400, 256, 0, stream>>>(O2, Wp2, p2b, OFb);
    k_unshuffle<<<320, 256, 0, stream>>>(OFb, out);
}

// Round 13
// 114.884 us; speedup vs baseline: 1.0252x; 1.0252x over previous
//
#include <hip/hip_runtime.h>
#include <hip/hip_bf16.h>

// GridAttention: B=2, C=64, H=W=160, INTERVAL=8, HEADS=4, d=16
// Bp=128, h=w=20, N=400 (padded to 416). Token-major [bp][n][c], c=head*16+dd.

#define N_TOK 400
#define NP    416
#define BP    128

typedef short bf16x8 __attribute__((ext_vector_type(8)));
typedef float f32x16 __attribute__((ext_vector_type(16)));

__device__ inline ushort f2bf(float f) {
    __hip_bfloat16 h = __float2bfloat16(f);
    return *reinterpret_cast<ushort*>(&h);
}
__device__ inline float bf2f(ushort u) {
    union { uint i; float f; } v; v.i = (uint)u << 16; return v.f;
}
__device__ inline uint pk2(float a, float b) {
    return (uint)f2bf(a) | ((uint)f2bf(b) << 16);
}
__device__ inline bf16x8 ld16(const ushort* p) {
    union { uint4 q; bf16x8 v; } u;
    u.q = *reinterpret_cast<const uint4*>(p);
    return u.v;
}
__device__ inline float fast_exp2(float x) {
#if __has_builtin(__builtin_amdgcn_exp2f)
    return __builtin_amdgcn_exp2f(x);
#else
    return __expf(x * 0.6931471805599453f);
#endif
}
__device__ inline float fast_rcp(float x) {
#if __has_builtin(__builtin_amdgcn_rcpf)
    return __builtin_amdgcn_rcpf(x);
#else
    return 1.0f / x;
#endif
}

#define L2E 1.4426950408889634f
#define QK_PRESCALE 0.36067376022224085f   // 0.25 * log2(e), folded into Qb/Kb at conv

// ---------------- K0: fused weight prep + bias MLP ----------------
// blocks [0,2704): biasF[h][qt][mt][lane][r] fp32, value = log2(e)*bias (fragment-major,
//   n = qt*32+(lane&31), m = mt*32+(r&3)+8*(r>>2)+4*(lane>>5)); 692224 floats.
// blocks [2704,2801): bf16 weight conversion + bias concat.
__global__ __launch_bounds__(256) void k_prep(
    const float* __restrict__ W1, const float* __restrict__ B1,
    const float* __restrict__ W2, const float* __restrict__ B2,
    const float* __restrict__ qkv_w, const float* __restrict__ qkv_b,
    const float* __restrict__ grid_w, const float* __restrict__ grid_b,
    const float* __restrict__ p1w, const float* __restrict__ p2w,
    float* __restrict__ biasF, ushort* __restrict__ Wc, float* __restrict__ Bc,
    ushort* __restrict__ Wp1, ushort* __restrict__ Wp2)
{
    int blk = blockIdx.x;
    if (blk < 2704) {
        int idx = blk * 256 + threadIdx.x;
        if (idx >= 692224) return;
        int r = idx & 15, lane = (idx >> 4) & 63;
        int tile = idx >> 10;
        int mt = tile % 13, rem = tile / 13, qt = rem % 13, h = rem / 13;
        int n = qt * 32 + (lane & 31);
        int m = mt * 32 + (r & 3) + 8 * (r >> 2) + 4 * (lane >> 5);
        float val = 0.0f;
        if (n < 400 && m < 400) {
            float r0 = (float)(n / 20 - m / 20) * (1.0f / 19.0f);
            float r1 = (float)(n % 20 - m % 20) * (1.0f / 19.0f);
            float o = B2[h];
#pragma unroll
            for (int k = 0; k < 16; ++k) {
                float hh = r0 * W1[k] + r1 * W1[16 + k] + B1[k];
                hh = fmaxf(hh, 0.0f);
                o += hh * W2[k * 4 + h];
            }
            val = o * L2E;   // exp2 domain; QK scale carried by Qb/Kb prescale
        }
        biasF[idx] = val;
    } else {
        int t = (blk - 2704) * 256 + threadIdx.x;
        if (t < 16384) {
            int oc = t >> 6, k = t & 63;
            float v = (oc < 192) ? qkv_w[oc * 64 + k] : grid_w[(oc - 192) * 64 + k];
            Wc[t] = f2bf(v);
        } else if (t < 16384 + 4096) {
            Wp1[t - 16384] = f2bf(p1w[t - 16384]);
        } else if (t < 16384 + 8192) {
            Wp2[t - 16384 - 4096] = f2bf(p2w[t - 16384 - 4096]);
        } else if (t < 16384 + 8192 + 256) {
            int oc = t - 16384 - 8192;
            Bc[oc] = (oc < 192) ? qkv_b[oc] : grid_b[oc - 192];
        }
    }
}

// ---------------- K2: fused qkv+grid conv1x1 as MFMA GEMM, shuffle on write ----------------
// Wave 0 -> Qb, 1 -> Kb (both pre-scaled by 0.25*log2e), 2 -> Vb, 3 -> XGb.
__global__ __launch_bounds__(256) void k_conv(
    const float* __restrict__ x, const ushort* __restrict__ Wc,
    const float* __restrict__ Bc,
    ushort* __restrict__ Qb, ushort* __restrict__ Kb,
    ushort* __restrict__ Vb, ushort* __restrict__ XGb)
{
    __shared__ __align__(16) ushort XL[32 * 64];
    int blk = blockIdx.x;                 // 1600 = 2*160*5
    int b = blk / 800, rem = blk % 800;
    int H0 = rem / 5, wt = rem % 5;
    int w0 = wt * 32;
    int tid = threadIdx.x;

    {
        int c = tid >> 2, q4 = tid & 3;
        const float* xr = x + ((size_t)(b * 64 + c) * 160 + H0) * 160 + w0 + q4 * 8;
        float4 f0 = *reinterpret_cast<const float4*>(xr);
        float4 f1 = *reinterpret_cast<const float4*>(xr + 4);
        char* base = reinterpret_cast<char*>(XL);
#pragma unroll
        for (int k = 0; k < 8; ++k) {
            float v = (k < 4) ? ((const float*)&f0)[k] : ((const float*)&f1)[k - 4];
            int p = q4 * 8 + k;
            int byt = p * 128 + ((2 * c) ^ ((p & 7) << 4));
            *reinterpret_cast<ushort*>(base + byt) = f2bf(v);
        }
    }

    int lane = tid & 63, w = tid >> 6;
    int l31 = lane & 31, hi = lane >> 5;

    bf16x8 wf[2][4];
#pragma unroll
    for (int nt = 0; nt < 2; ++nt)
#pragma unroll
        for (int kk = 0; kk < 4; ++kk)
            wf[nt][kk] = ld16(&Wc[(size_t)(w * 64 + nt * 32 + l31) * 64 + kk * 16 + hi * 8]);
    __syncthreads();

    f32x16 acc0 = 0.0f, acc1 = 0.0f;
    const char* base = reinterpret_cast<const char*>(XL);
#pragma unroll
    for (int kk = 0; kk < 4; ++kk) {
        int byt = l31 * 128 + (((kk * 32 + hi * 16)) ^ ((l31 & 7) << 4));
        bf16x8 xf;
        {
            union { uint4 q; bf16x8 v; } u;
            u.q = *reinterpret_cast<const uint4*>(base + byt);
            xf = u.v;
        }
        acc0 = __builtin_amdgcn_mfma_f32_32x32x16_bf16(wf[0][kk], xf, acc0, 0, 0, 0);
        acc1 = __builtin_amdgcn_mfma_f32_32x32x16_bf16(wf[1][kk], xf, acc1, 0, 0, 0);
    }

    int W0 = w0 + l31, ww = W0 >> 3, j = W0 & 7;
    int bp = b * 64 + (H0 & 7) * 8 + j;
    int n  = (H0 >> 3) * 20 + ww;
    ushort* outb = (w == 0) ? Qb : (w == 1) ? Kb : (w == 2) ? Vb : XGb;
    float mul = (w <= 1) ? QK_PRESCALE : 1.0f;
    ushort* dst = outb + ((size_t)bp * NP + n) * 64;
#pragma unroll
    for (int nt = 0; nt < 2; ++nt) {
        const f32x16& a = nt ? acc1 : acc0;
#pragma unroll
        for (int g = 0; g < 4; ++g) {
            int cc = nt * 32 + 8 * g + 4 * hi;
            int oc = w * 64 + cc;
            uint2 uu;
            uu.x = pk2((a[4 * g + 0] + Bc[oc + 0]) * mul, (a[4 * g + 1] + Bc[oc + 1]) * mul);
            uu.y = pk2((a[4 * g + 2] + Bc[oc + 2]) * mul, (a[4 * g + 3] + Bc[oc + 3]) * mul);
            *reinterpret_cast<uint2*>(dst + cc) = uu;
        }
    }
}

// ---------------- K3: MFMA attention (r11 structure + ones-rows Vt) ----------------
// Grid 512 = (bp, head); 8 waves. Wave w owns q-tiles {w, w+8} (13 total).
// Bias via MFMA C-operand, fragment-major f32x16 loads, double-buffer prefetched.
// Vt rows 16..31 pre-filled with bf16 1.0 -> unconditional PV B-load; acc cols
// 16..31 accumulate the softmax denominator for free.
__global__ __launch_bounds__(512, 4) void k_attn_mfma(
    const ushort* __restrict__ Qg, const ushort* __restrict__ Kg,
    const ushort* __restrict__ Vg, const float* __restrict__ biasF,
    ushort* __restrict__ O)
{
    __shared__ ushort Ks[NP * 16];    // [m][d]
    __shared__ ushort Vt[32 * 424];   // [d][m]; rows 16..31 = bf16 1.0
    int blk = blockIdx.x;
    int bp = blk >> 2, h = blk & 3;
    int tid = threadIdx.x;

    const ushort* Ksrc = Kg + (size_t)bp * NP * 64 + h * 16;
#pragma unroll
    for (int it = 0; it < 2; ++it) {
        int i = tid + it * 512;
        if (i < NP * 2) {
            int row = i >> 1, half = i & 1;
            *reinterpret_cast<uint4*>(&Ks[row * 16 + half * 8]) =
                *reinterpret_cast<const uint4*>(&Ksrc[(size_t)row * 64 + half * 8]);
        }
    }
    const ushort* Vsrc = Vg + (size_t)bp * NP * 64 + h * 16;
#pragma unroll
    for (int it = 0; it < 2; ++it) {
        int i = tid + it * 512;
        if (i < 800) {
            int row = i >> 1, hf = i & 1;
            uint4 v = *reinterpret_cast<const uint4*>(&Vsrc[(size_t)row * 64 + hf * 8]);
            const ushort* pv = reinterpret_cast<const ushort*>(&v);
#pragma unroll
            for (int k = 0; k < 8; ++k)
                Vt[(hf * 8 + k) * 424 + row] = pv[k];
        }
    }
    // ones rows 16..31 (212 uints per row, 3392 total)
    for (int j = tid; j < 3392; j += 512) {
        int row = 16 + j / 212, col2 = j % 212;
        *reinterpret_cast<uint*>(&Vt[row * 424 + col2 * 2]) = 0x3F803F80u;
    }
    __syncthreads();

    int lane = tid & 63, w = tid >> 6;
    int l31 = lane & 31, hi = lane >> 5;

    for (int qt = w; qt < 13; qt += 8) {
        int qbase = qt * 32;
        bf16x8 qf = ld16(&Qg[((size_t)bp * NP + qbase + l31) * 64 + h * 16 + hi * 8]);
        f32x16 acc = 0.0f;
        const f32x16* bfr = reinterpret_cast<const f32x16*>(
            biasF + ((size_t)(h * 169 + qt * 13)) * 1024 + lane * 16);

        f32x16 cb = bfr[0];

#pragma unroll
        for (int mt = 0; mt < 13; ++mt) {
            const int mbase = mt * 32;
            f32x16 nb;
            if (mt < 12) nb = bfr[mt + 1];   // prefetch next tile's bias (prio 0)

            __builtin_amdgcn_s_setprio(1);
            bf16x8 kf = ld16(&Ks[(mbase + l31) * 16 + hi * 8]);
            f32x16 sv = __builtin_amdgcn_mfma_f32_32x32x16_bf16(kf, qf, cb, 0, 0, 0);

            const int nv = (mt == 12) ? 8 : 16;
            float p[16];
#pragma unroll
            for (int r = 0; r < 16; ++r)
                if (r < nv) p[r] = fast_exp2(sv[r]);

            // B-operand rows: Vt rows <16 = V^T, rows >=16 = 1.0 (denominator columns)
            {
                uint c4 = pk2(p[0], p[1]), c5 = pk2(p[2], p[3]);
                uint c6 = pk2(p[4], p[5]), c7 = pk2(p[6], p[7]);
                asm("v_permlane32_swap_b32 %0, %1" : "+v"(c4), "+v"(c6));
                asm("v_permlane32_swap_b32 %0, %1" : "+v"(c5), "+v"(c7));
                union { uint u[4]; bf16x8 v; } A;
                A.u[0] = c4; A.u[1] = c5; A.u[2] = c6; A.u[3] = c7;
                bf16x8 vf = ld16(&Vt[l31 * 424 + mbase + hi * 8]);
                acc = __builtin_amdgcn_mfma_f32_32x32x16_bf16(A.v, vf, acc, 0, 0, 0);
            }
            if (mt < 12) {
                uint c4 = pk2(p[8], p[9]),  c5 = pk2(p[10], p[11]);
                uint c6 = pk2(p[12], p[13]), c7 = pk2(p[14], p[15]);
                asm("v_permlane32_swap_b32 %0, %1" : "+v"(c4), "+v"(c6));
                asm("v_permlane32_swap_b32 %0, %1" : "+v"(c5), "+v"(c7));
                union { uint u[4]; bf16x8 v; } A;
                A.u[0] = c4; A.u[1] = c5; A.u[2] = c6; A.u[3] = c7;
                bf16x8 vf = ld16(&Vt[l31 * 424 + mbase + 16 + hi * 8]);
                acc = __builtin_amdgcn_mfma_f32_32x32x16_bf16(A.v, vf, acc, 0, 0, 0);
            }
            __builtin_amdgcn_s_setprio(0);
            cb = nb;
        }

        // normalize + store: denominator for row r sits in lane (lane|16), same register.
#pragma unroll
        for (int r = 0; r < 16; ++r) {
            int moff = (r & 3) + 8 * (r >> 2) + 4 * hi;
            int q = qbase + moff;
            float s = __shfl(acc[r], lane | 16);
            if (l31 < 16 && q < N_TOK)
                O[((size_t)bp * 400 + q) * 64 + h * 16 + l31] = f2bf(acc[r] * fast_rcp(s));
        }
    }
}

// ---------------- K4: 64x64 proj as MFMA GEMM (bf16 in, bf16 out) ----------------
// MODE 0: out NP-padded token-major (for attn V input). MODE 1: out contiguous token-major.
template<int MODE>
__global__ __launch_bounds__(256) void k_proj(
    const ushort* __restrict__ In, const ushort* __restrict__ Wp,
    const float* __restrict__ Bv, ushort* __restrict__ Out)
{
    __shared__ __align__(16) ushort XL[128 * 64];
    size_t t0 = (size_t)blockIdx.x * 128;
    int tid = threadIdx.x;

    char* basec = reinterpret_cast<char*>(XL);
#pragma unroll
    for (int it = 0; it < 4; ++it) {
        int idx = tid + it * 256;
        int p = idx >> 3, c8 = idx & 7;
        uint4 v = *reinterpret_cast<const uint4*>(In + (t0 + p) * 64 + c8 * 8);
        int byt = p * 128 + ((c8 * 16) ^ ((p & 7) << 4));
        *reinterpret_cast<uint4*>(basec + byt) = v;
    }

    int lane = tid & 63, w = tid >> 6;
    int l31 = lane & 31, hi = lane >> 5;

    bf16x8 wf[2][4];
#pragma unroll
    for (int nt = 0; nt < 2; ++nt)
#pragma unroll
        for (int kk = 0; kk < 4; ++kk)
            wf[nt][kk] = ld16(&Wp[(size_t)(nt * 32 + l31) * 64 + kk * 16 + hi * 8]);
    __syncthreads();

    int prow = w * 32 + l31;
    f32x16 acc0 = 0.0f, acc1 = 0.0f;
#pragma unroll
    for (int kk = 0; kk < 4; ++kk) {
        int byt = prow * 128 + (((kk * 32 + hi * 16)) ^ ((prow & 7) << 4));
        union { uint4 q; bf16x8 v; } u;
        u.q = *reinterpret_cast<const uint4*>(basec + byt);
        acc0 = __builtin_amdgcn_mfma_f32_32x32x16_bf16(wf[0][kk], u.v, acc0, 0, 0, 0);
        acc1 = __builtin_amdgcn_mfma_f32_32x32x16_bf16(wf[1][kk], u.v, acc1, 0, 0, 0);
    }

    size_t t = t0 + prow;
    ushort* dst;
    if (MODE == 0) {
        int bp = (int)(t / 400), n = (int)(t % 400);
        dst = Out + ((size_t)bp * NP + n) * 64;
    } else {
        dst = Out + t * 64;
    }
#pragma unroll
    for (int nt = 0; nt < 2; ++nt) {
        const f32x16& a = nt ? acc1 : acc0;
#pragma unroll
        for (int g = 0; g < 4; ++g) {
            int cc = nt * 32 + 8 * g + 4 * hi;
            uint2 uu;
            uu.x = pk2(a[4 * g + 0] + Bv[cc + 0], a[4 * g + 1] + Bv[cc + 1]);
            uu.y = pk2(a[4 * g + 2] + Bv[cc + 2], a[4 * g + 3] + Bv[cc + 3]);
            *reinterpret_cast<uint2*>(dst + cc) = uu;
        }
    }
}

// ---------------- K5: grid_unshuffle (token-major bf16 -> [B][C][160][160] fp32) ----------------
__global__ __launch_bounds__(256) void k_unshuffle(
    const ushort* __restrict__ In, float* __restrict__ out)
{
    __shared__ __align__(16) ushort il[160 * 64];
    int blk = blockIdx.x;
    int b = blk / 160, rem = blk % 160, iI = rem / 20, hh = rem % 20;
    int tid = threadIdx.x;

    for (int idx = tid; idx < 1280; idx += 256) {
        int j = idx / 160, r2 = idx % 160, ww = r2 / 8, c8 = r2 % 8;
        int bp = b * 64 + iI * 8 + j;
        int n  = hh * 20 + ww;
        uint4 v = reinterpret_cast<const uint4*>(In + ((size_t)bp * 400 + n) * 64)[c8];
        reinterpret_cast<uint4*>(&il[(ww * 8 + j) * 64])[c8] = v;
    }
    __syncthreads();

    int c = tid >> 2, q = tid & 3;
    int H0 = hh * 8 + iI;
    float* og = out + ((size_t)(b * 64 + c) * 160 + H0) * 160;
#pragma unroll
    for (int k = 0; k < 10; ++k) {
        int f = q + 4 * k;
        float4 v;
        v.x = bf2f(il[(4 * f + 0) * 64 + c]);
        v.y = bf2f(il[(4 * f + 1) * 64 + c]);
        v.z = bf2f(il[(4 * f + 2) * 64 + c]);
        v.w = bf2f(il[(4 * f + 3) * 64 + c]);
        reinterpret_cast<float4*>(og)[f] = v;
    }
}

extern "C" void kernel_launch(void* const* d_in, const int* in_sizes, int n_in,
                              void* d_out, int out_size, void* d_ws, size_t ws_size,
                              hipStream_t stream)
{
    const float* x      = (const float*)d_in[0];
    const float* qkv_w  = (const float*)d_in[1];
    const float* qkv_b  = (const float*)d_in[2];
    const float* grid_w = (const float*)d_in[3];
    const float* grid_b = (const float*)d_in[4];
    const float* pw1    = (const float*)d_in[5];
    const float* pb1    = (const float*)d_in[6];
    const float* pw2    = (const float*)d_in[7];
    const float* pb2    = (const float*)d_in[8];
    const float* p1w    = (const float*)d_in[9];
    const float* p1b    = (const float*)d_in[10];
    const float* p2w    = (const float*)d_in[11];
    const float* p2b    = (const float*)d_in[12];

    // workspace layout (byte offsets, all 16B-aligned)
    char* W = (char*)d_ws;
    float*  biasF = (float*)(W + 0);             // 692224*4 = 2,768,896
    ushort* Wc    = (ushort*)(W + 2768896);      // 32,768
    ushort* Wp1   = (ushort*)(W + 2801664);      //  8,192
    ushort* Wp2   = (ushort*)(W + 2809856);      //  8,192
    float*  Bc    = (float*) (W + 2818048);      //  1,024
    const size_t BASE2 = 2819072;
    const size_t BB = (size_t)BP * NP * 64 * 2;  // 6,815,744 per bf16 NP buffer
    ushort* Qb = (ushort*)(W + BASE2);
    ushort* Kb = (ushort*)(W + BASE2 + 1 * BB);
    ushort* Vb = (ushort*)(W + BASE2 + 2 * BB);
    ushort* XG = (ushort*)(W + BASE2 + 3 * BB);
    ushort* P1 = (ushort*)(W + BASE2 + 4 * BB);
    const size_t OB = (size_t)BP * 400 * 64 * 2; // 6,553,600 per bf16 contiguous buffer
    ushort* O1 = (ushort*)(W + BASE2 + 5 * BB);
    ushort* O2 = (ushort*)(W + BASE2 + 5 * BB + OB);
    ushort* OFb = O1;   // proj2 output reuses O1 (dead after proj1)
    float*  out = (float*)d_out;

    k_prep<<<2801, 256, 0, stream>>>(pw1, pb1, pw2, pb2, qkv_w, qkv_b, grid_w, grid_b,
                                     p1w, p2w, biasF, Wc, Bc, Wp1, Wp2);
    k_conv<<<1600, 256, 0, stream>>>(x, Wc, Bc, Qb, Kb, Vb, XG);
    // attn1: q=XG, k=Kb(prescaled), v=Vb -> O1; proj1 -> P1 (bf16, NP-padded)
    k_attn_mfma<<<512, 512, 0, stream>>>(XG, Kb, Vb, biasF, O1);
    k_proj<0><<<400, 256, 0, stream>>>(O1, Wp1, p1b, P1);
    // attn2: q=Qb(prescaled), k=XG, v=P1 -> O2; proj2 -> OFb (bf16, overlays O1)
    k_attn_mfma<<<512, 512, 0, stream>>>(Qb, XG, P1, biasF, O2);
    k_proj<1><<<400, 256, 0, stream>>>(O2, Wp2, p2b, OFb);
    k_unshuffle<<<320, 256, 0, stream>>>(OFb, out);
}

// Round 14
// 112.716 us; speedup vs baseline: 1.0450x; 1.0192x over previous
//
#include <hip/hip_runtime.h>
#include <hip/hip_bf16.h>

// GridAttention: B=2, C=64, H=W=160, INTERVAL=8, HEADS=4, d=16
// Bp=128, h=w=20, N=400 (padded to 416). Token-major [bp][n][c], c=head*16+dd.

#define N_TOK 400
#define NP    416
#define BP    128

typedef short bf16x8 __attribute__((ext_vector_type(8)));
typedef float f32x16 __attribute__((ext_vector_type(16)));

__device__ inline ushort f2bf(float f) {
    __hip_bfloat16 h = __float2bfloat16(f);
    return *reinterpret_cast<ushort*>(&h);
}
__device__ inline float bf2f(ushort u) {
    union { uint i; float f; } v; v.i = (uint)u << 16; return v.f;
}
__device__ inline uint pk2(float a, float b) {
    return (uint)f2bf(a) | ((uint)f2bf(b) << 16);
}
__device__ inline bf16x8 ld16(const ushort* p) {
    union { uint4 q; bf16x8 v; } u;
    u.q = *reinterpret_cast<const uint4*>(p);
    return u.v;
}
__device__ inline float fast_exp2(float x) {
#if __has_builtin(__builtin_amdgcn_exp2f)
    return __builtin_amdgcn_exp2f(x);
#else
    return __expf(x * 0.6931471805599453f);
#endif
}
__device__ inline float fast_rcp(float x) {
#if __has_builtin(__builtin_amdgcn_rcpf)
    return __builtin_amdgcn_rcpf(x);
#else
    return 1.0f / x;
#endif
}

#define L2E 1.4426950408889634f
#define QK_PRESCALE 0.36067376022224085f   // 0.25 * log2(e), folded into Qb/Kb at conv

// ---------------- K-1: bias MLP table (only 4*39*39 = 6084 unique values) ----------------
__global__ __launch_bounds__(256) void k_tab(
    const float* __restrict__ W1, const float* __restrict__ B1,
    const float* __restrict__ W2, const float* __restrict__ B2,
    float* __restrict__ table)
{
    int idx = blockIdx.x * 256 + threadIdx.x;
    if (idx >= 6084) return;
    int h = idx / 1521, rem = idx % 1521;
    float r0 = (float)(rem / 39 - 19) * (1.0f / 19.0f);
    float r1 = (float)(rem % 39 - 19) * (1.0f / 19.0f);
    float o = B2[h];
#pragma unroll
    for (int k = 0; k < 16; ++k) {
        float hh = r0 * W1[k] + r1 * W1[16 + k] + B1[k];
        hh = fmaxf(hh, 0.0f);
        o += hh * W2[k * 4 + h];
    }
    table[idx] = o * L2E;   // exp2 domain; QK scale carried by Qb/Kb prescale
}

// ---------------- K0: fragment-major bias expansion (gather) + weight prep ----------------
// blocks [0,2704): biasF[h][qt][mt][lane][r] fp32 via table gather (fragment-major,
//   n = qt*32+(lane&31), m = mt*32+(r&3)+8*(r>>2)+4*(lane>>5)); 692224 floats.
// blocks [2704,2801): bf16 weight conversion + bias concat.
__global__ __launch_bounds__(256) void k_prep(
    const float* __restrict__ table,
    const float* __restrict__ qkv_w, const float* __restrict__ qkv_b,
    const float* __restrict__ grid_w, const float* __restrict__ grid_b,
    const float* __restrict__ p1w, const float* __restrict__ p2w,
    float* __restrict__ biasF, ushort* __restrict__ Wc, float* __restrict__ Bc,
    ushort* __restrict__ Wp1, ushort* __restrict__ Wp2)
{
    int blk = blockIdx.x;
    if (blk < 2704) {
        int idx = blk * 256 + threadIdx.x;
        if (idx >= 692224) return;
        int r = idx & 15, lane = (idx >> 4) & 63;
        int tile = idx >> 10;
        int mt = tile % 13, rem = tile / 13, qt = rem % 13, h = rem / 13;
        int n = qt * 32 + (lane & 31);
        int m = mt * 32 + (r & 3) + 8 * (r >> 2) + 4 * (lane >> 5);
        float val = 0.0f;
        if (n < 400 && m < 400) {
            int dh = n / 20 - m / 20 + 19;
            int dw = n % 20 - m % 20 + 19;
            val = table[h * 1521 + dh * 39 + dw];
        }
        biasF[idx] = val;
    } else {
        int t = (blk - 2704) * 256 + threadIdx.x;
        if (t < 16384) {
            int oc = t >> 6, k = t & 63;
            float v = (oc < 192) ? qkv_w[oc * 64 + k] : grid_w[(oc - 192) * 64 + k];
            Wc[t] = f2bf(v);
        } else if (t < 16384 + 4096) {
            Wp1[t - 16384] = f2bf(p1w[t - 16384]);
        } else if (t < 16384 + 8192) {
            Wp2[t - 16384 - 4096] = f2bf(p2w[t - 16384 - 4096]);
        } else if (t < 16384 + 8192 + 256) {
            int oc = t - 16384 - 8192;
            Bc[oc] = (oc < 192) ? qkv_b[oc] : grid_b[oc - 192];
        }
    }
}

// ---------------- K2: fused qkv+grid conv1x1 as MFMA GEMM, shuffle on write ----------------
// Wave 0 -> Qb, 1 -> Kb (both pre-scaled by 0.25*log2e), 2 -> Vb, 3 -> XGb.
__global__ __launch_bounds__(256) void k_conv(
    const float* __restrict__ x, const ushort* __restrict__ Wc,
    const float* __restrict__ Bc,
    ushort* __restrict__ Qb, ushort* __restrict__ Kb,
    ushort* __restrict__ Vb, ushort* __restrict__ XGb)
{
    __shared__ __align__(16) ushort XL[32 * 64];
    int blk = blockIdx.x;                 // 1600 = 2*160*5
    int b = blk / 800, rem = blk % 800;
    int H0 = rem / 5, wt = rem % 5;
    int w0 = wt * 32;
    int tid = threadIdx.x;

    {
        int c = tid >> 2, q4 = tid & 3;
        const float* xr = x + ((size_t)(b * 64 + c) * 160 + H0) * 160 + w0 + q4 * 8;
        float4 f0 = *reinterpret_cast<const float4*>(xr);
        float4 f1 = *reinterpret_cast<const float4*>(xr + 4);
        char* base = reinterpret_cast<char*>(XL);
#pragma unroll
        for (int k = 0; k < 8; ++k) {
            float v = (k < 4) ? ((const float*)&f0)[k] : ((const float*)&f1)[k - 4];
            int p = q4 * 8 + k;
            int byt = p * 128 + ((2 * c) ^ ((p & 7) << 4));
            *reinterpret_cast<ushort*>(base + byt) = f2bf(v);
        }
    }

    int lane = tid & 63, w = tid >> 6;
    int l31 = lane & 31, hi = lane >> 5;

    bf16x8 wf[2][4];
#pragma unroll
    for (int nt = 0; nt < 2; ++nt)
#pragma unroll
        for (int kk = 0; kk < 4; ++kk)
            wf[nt][kk] = ld16(&Wc[(size_t)(w * 64 + nt * 32 + l31) * 64 + kk * 16 + hi * 8]);
    __syncthreads();

    f32x16 acc0 = 0.0f, acc1 = 0.0f;
    const char* base = reinterpret_cast<const char*>(XL);
#pragma unroll
    for (int kk = 0; kk < 4; ++kk) {
        int byt = l31 * 128 + (((kk * 32 + hi * 16)) ^ ((l31 & 7) << 4));
        bf16x8 xf;
        {
            union { uint4 q; bf16x8 v; } u;
            u.q = *reinterpret_cast<const uint4*>(base + byt);
            xf = u.v;
        }
        acc0 = __builtin_amdgcn_mfma_f32_32x32x16_bf16(wf[0][kk], xf, acc0, 0, 0, 0);
        acc1 = __builtin_amdgcn_mfma_f32_32x32x16_bf16(wf[1][kk], xf, acc1, 0, 0, 0);
    }

    int W0 = w0 + l31, ww = W0 >> 3, j = W0 & 7;
    int bp = b * 64 + (H0 & 7) * 8 + j;
    int n  = (H0 >> 3) * 20 + ww;
    ushort* outb = (w == 0) ? Qb : (w == 1) ? Kb : (w == 2) ? Vb : XGb;
    float mul = (w <= 1) ? QK_PRESCALE : 1.0f;
    ushort* dst = outb + ((size_t)bp * NP + n) * 64;
#pragma unroll
    for (int nt = 0; nt < 2; ++nt) {
        const f32x16& a = nt ? acc1 : acc0;
#pragma unroll
        for (int g = 0; g < 4; ++g) {
            int cc = nt * 32 + 8 * g + 4 * hi;
            int oc = w * 64 + cc;
            uint2 uu;
            uu.x = pk2((a[4 * g + 0] + Bc[oc + 0]) * mul, (a[4 * g + 1] + Bc[oc + 1]) * mul);
            uu.y = pk2((a[4 * g + 2] + Bc[oc + 2]) * mul, (a[4 * g + 3] + Bc[oc + 3]) * mul);
            *reinterpret_cast<uint2*>(dst + cc) = uu;
        }
    }
}

// ---------------- K3: MFMA attention (r11 structure + ones-rows Vt) ----------------
// Grid 512 = (bp, head); 8 waves. Wave w owns q-tiles {w, w+8} (13 total).
// Bias via MFMA C-operand, fragment-major f32x16 loads, double-buffer prefetched.
// Vt rows 16..31 pre-filled with bf16 1.0 -> unconditional PV B-load; acc cols
// 16..31 accumulate the softmax denominator for free.
__global__ __launch_bounds__(512, 4) void k_attn_mfma(
    const ushort* __restrict__ Qg, const ushort* __restrict__ Kg,
    const ushort* __restrict__ Vg, const float* __restrict__ biasF,
    ushort* __restrict__ O)
{
    __shared__ ushort Ks[NP * 16];    // [m][d]
    __shared__ ushort Vt[32 * 424];   // [d][m]; rows 16..31 = bf16 1.0
    int blk = blockIdx.x;
    int bp = blk >> 2, h = blk & 3;
    int tid = threadIdx.x;

    const ushort* Ksrc = Kg + (size_t)bp * NP * 64 + h * 16;
#pragma unroll
    for (int it = 0; it < 2; ++it) {
        int i = tid + it * 512;
        if (i < NP * 2) {
            int row = i >> 1, half = i & 1;
            *reinterpret_cast<uint4*>(&Ks[row * 16 + half * 8]) =
                *reinterpret_cast<const uint4*>(&Ksrc[(size_t)row * 64 + half * 8]);
        }
    }
    const ushort* Vsrc = Vg + (size_t)bp * NP * 64 + h * 16;
#pragma unroll
    for (int it = 0; it < 2; ++it) {
        int i = tid + it * 512;
        if (i < 800) {
            int row = i >> 1, hf = i & 1;
            uint4 v = *reinterpret_cast<const uint4*>(&Vsrc[(size_t)row * 64 + hf * 8]);
            const ushort* pv = reinterpret_cast<const ushort*>(&v);
#pragma unroll
            for (int k = 0; k < 8; ++k)
                Vt[(hf * 8 + k) * 424 + row] = pv[k];
        }
    }
    // ones rows 16..31 (212 uints per row, 3392 total)
    for (int j = tid; j < 3392; j += 512) {
        int row = 16 + j / 212, col2 = j % 212;
        *reinterpret_cast<uint*>(&Vt[row * 424 + col2 * 2]) = 0x3F803F80u;
    }
    __syncthreads();

    int lane = tid & 63, w = tid >> 6;
    int l31 = lane & 31, hi = lane >> 5;

    for (int qt = w; qt < 13; qt += 8) {
        int qbase = qt * 32;
        bf16x8 qf = ld16(&Qg[((size_t)bp * NP + qbase + l31) * 64 + h * 16 + hi * 8]);
        f32x16 acc = 0.0f;
        const f32x16* bfr = reinterpret_cast<const f32x16*>(
            biasF + ((size_t)(h * 169 + qt * 13)) * 1024 + lane * 16);

        f32x16 cb = bfr[0];

#pragma unroll
        for (int mt = 0; mt < 13; ++mt) {
            const int mbase = mt * 32;
            f32x16 nb;
            if (mt < 12) nb = bfr[mt + 1];   // prefetch next tile's bias (prio 0)

            __builtin_amdgcn_s_setprio(1);
            bf16x8 kf = ld16(&Ks[(mbase + l31) * 16 + hi * 8]);
            f32x16 sv = __builtin_amdgcn_mfma_f32_32x32x16_bf16(kf, qf, cb, 0, 0, 0);

            const int nv = (mt == 12) ? 8 : 16;
            float p[16];
#pragma unroll
            for (int r = 0; r < 16; ++r)
                if (r < nv) p[r] = fast_exp2(sv[r]);

            // B-operand rows: Vt rows <16 = V^T, rows >=16 = 1.0 (denominator columns)
            {
                uint c4 = pk2(p[0], p[1]), c5 = pk2(p[2], p[3]);
                uint c6 = pk2(p[4], p[5]), c7 = pk2(p[6], p[7]);
                asm("v_permlane32_swap_b32 %0, %1" : "+v"(c4), "+v"(c6));
                asm("v_permlane32_swap_b32 %0, %1" : "+v"(c5), "+v"(c7));
                union { uint u[4]; bf16x8 v; } A;
                A.u[0] = c4; A.u[1] = c5; A.u[2] = c6; A.u[3] = c7;
                bf16x8 vf = ld16(&Vt[l31 * 424 + mbase + hi * 8]);
                acc = __builtin_amdgcn_mfma_f32_32x32x16_bf16(A.v, vf, acc, 0, 0, 0);
            }
            if (mt < 12) {
                uint c4 = pk2(p[8], p[9]),  c5 = pk2(p[10], p[11]);
                uint c6 = pk2(p[12], p[13]), c7 = pk2(p[14], p[15]);
                asm("v_permlane32_swap_b32 %0, %1" : "+v"(c4), "+v"(c6));
                asm("v_permlane32_swap_b32 %0, %1" : "+v"(c5), "+v"(c7));
                union { uint u[4]; bf16x8 v; } A;
                A.u[0] = c4; A.u[1] = c5; A.u[2] = c6; A.u[3] = c7;
                bf16x8 vf = ld16(&Vt[l31 * 424 + mbase + 16 + hi * 8]);
                acc = __builtin_amdgcn_mfma_f32_32x32x16_bf16(A.v, vf, acc, 0, 0, 0);
            }
            __builtin_amdgcn_s_setprio(0);
            cb = nb;
        }

        // normalize + store: denominator for row r sits in lane (lane|16), same register.
#pragma unroll
        for (int r = 0; r < 16; ++r) {
            int moff = (r & 3) + 8 * (r >> 2) + 4 * hi;
            int q = qbase + moff;
            float s = __shfl(acc[r], lane | 16);
            if (l31 < 16 && q < N_TOK)
                O[((size_t)bp * 400 + q) * 64 + h * 16 + l31] = f2bf(acc[r] * fast_rcp(s));
        }
    }
}

// ---------------- K4: 64x64 proj as MFMA GEMM (bf16 in, bf16 out, NP-padded) ----------------
__global__ __launch_bounds__(256) void k_proj(
    const ushort* __restrict__ In, const ushort* __restrict__ Wp,
    const float* __restrict__ Bv, ushort* __restrict__ Out)
{
    __shared__ __align__(16) ushort XL[128 * 64];
    size_t t0 = (size_t)blockIdx.x * 128;
    int tid = threadIdx.x;

    char* basec = reinterpret_cast<char*>(XL);
#pragma unroll
    for (int it = 0; it < 4; ++it) {
        int idx = tid + it * 256;
        int p = idx >> 3, c8 = idx & 7;
        uint4 v = *reinterpret_cast<const uint4*>(In + (t0 + p) * 64 + c8 * 8);
        int byt = p * 128 + ((c8 * 16) ^ ((p & 7) << 4));
        *reinterpret_cast<uint4*>(basec + byt) = v;
    }

    int lane = tid & 63, w = tid >> 6;
    int l31 = lane & 31, hi = lane >> 5;

    bf16x8 wf[2][4];
#pragma unroll
    for (int nt = 0; nt < 2; ++nt)
#pragma unroll
        for (int kk = 0; kk < 4; ++kk)
            wf[nt][kk] = ld16(&Wp[(size_t)(nt * 32 + l31) * 64 + kk * 16 + hi * 8]);
    __syncthreads();

    int prow = w * 32 + l31;
    f32x16 acc0 = 0.0f, acc1 = 0.0f;
#pragma unroll
    for (int kk = 0; kk < 4; ++kk) {
        int byt = prow * 128 + (((kk * 32 + hi * 16)) ^ ((prow & 7) << 4));
        union { uint4 q; bf16x8 v; } u;
        u.q = *reinterpret_cast<const uint4*>(basec + byt);
        acc0 = __builtin_amdgcn_mfma_f32_32x32x16_bf16(wf[0][kk], u.v, acc0, 0, 0, 0);
        acc1 = __builtin_amdgcn_mfma_f32_32x32x16_bf16(wf[1][kk], u.v, acc1, 0, 0, 0);
    }

    size_t t = t0 + prow;
    int bp = (int)(t / 400), n = (int)(t % 400);
    ushort* dst = Out + ((size_t)bp * NP + n) * 64;
#pragma unroll
    for (int nt = 0; nt < 2; ++nt) {
        const f32x16& a = nt ? acc1 : acc0;
#pragma unroll
        for (int g = 0; g < 4; ++g) {
            int cc = nt * 32 + 8 * g + 4 * hi;
            uint2 uu;
            uu.x = pk2(a[4 * g + 0] + Bv[cc + 0], a[4 * g + 1] + Bv[cc + 1]);
            uu.y = pk2(a[4 * g + 2] + Bv[cc + 2], a[4 * g + 3] + Bv[cc + 3]);
            *reinterpret_cast<uint2*>(dst + cc) = uu;
        }
    }
}

// ---------------- K5: fused proj2 + grid_unshuffle ----------------
// Block = (b, H0) output row. Gathers the row's 160 tokens from token-major bf16 In,
// MFMA-projects, writes fp32 [B][C][160][160] directly (coalesced 32-pixel runs).
__global__ __launch_bounds__(256) void k_proj_out(
    const ushort* __restrict__ In, const ushort* __restrict__ Wp,
    const float* __restrict__ Bv, float* __restrict__ out)
{
    __shared__ __align__(16) ushort XL[160 * 64];
    int blk = blockIdx.x;        // 320 = 2*160
    int b = blk / 160, H0 = blk % 160;
    int hh = H0 >> 3, iI = H0 & 7;
    int tid = threadIdx.x;

    char* basec = reinterpret_cast<char*>(XL);
    for (int i = tid; i < 1280; i += 256) {
        int px = i >> 3, c8 = i & 7;
        int ww = px >> 3, j = px & 7;
        int bp = b * 64 + iI * 8 + j;
        int n  = hh * 20 + ww;
        uint4 v = *reinterpret_cast<const uint4*>(In + ((size_t)bp * 400 + n) * 64 + c8 * 8);
        int byt = px * 128 + ((c8 * 16) ^ ((px & 7) << 4));
        *reinterpret_cast<uint4*>(basec + byt) = v;
    }

    int lane = tid & 63, w = tid >> 6;
    int l31 = lane & 31, hi = lane >> 5;

    bf16x8 wf[2][4];
#pragma unroll
    for (int nt = 0; nt < 2; ++nt)
#pragma unroll
        for (int kk = 0; kk < 4; ++kk)
            wf[nt][kk] = ld16(&Wp[(size_t)(nt * 32 + l31) * 64 + kk * 16 + hi * 8]);
    __syncthreads();

    const size_t obase0 = (size_t)b * 64 * 25600 + (size_t)H0 * 160;
    for (int pt = w; pt < 5; pt += 4) {
        int prow = pt * 32 + l31;   // = W0
        f32x16 acc0 = 0.0f, acc1 = 0.0f;
#pragma unroll
        for (int kk = 0; kk < 4; ++kk) {
            int byt = prow * 128 + (((kk * 32 + hi * 16)) ^ ((prow & 7) << 4));
            union { uint4 q; bf16x8 v; } u;
            u.q = *reinterpret_cast<const uint4*>(basec + byt);
            acc0 = __builtin_amdgcn_mfma_f32_32x32x16_bf16(wf[0][kk], u.v, acc0, 0, 0, 0);
            acc1 = __builtin_amdgcn_mfma_f32_32x32x16_bf16(wf[1][kk], u.v, acc1, 0, 0, 0);
        }

#pragma unroll
        for (int nt = 0; nt < 2; ++nt) {
            const f32x16& a = nt ? acc1 : acc0;
#pragma unroll
            for (int g = 0; g < 4; ++g) {
                int cc = nt * 32 + 8 * g + 4 * hi;
#pragma unroll
                for (int k = 0; k < 4; ++k) {
                    int ch = cc + k;
                    out[obase0 + (size_t)ch * 25600 + prow] = a[4 * g + k] + Bv[ch];
                }
            }
        }
    }
}

extern "C" void kernel_launch(void* const* d_in, const int* in_sizes, int n_in,
                              void* d_out, int out_size, void* d_ws, size_t ws_size,
                              hipStream_t stream)
{
    const float* x      = (const float*)d_in[0];
    const float* qkv_w  = (const float*)d_in[1];
    const float* qkv_b  = (const float*)d_in[2];
    const float* grid_w = (const float*)d_in[3];
    const float* grid_b = (const float*)d_in[4];
    const float* pw1    = (const float*)d_in[5];
    const float* pb1    = (const float*)d_in[6];
    const float* pw2    = (const float*)d_in[7];
    const float* pb2    = (const float*)d_in[8];
    const float* p1w    = (const float*)d_in[9];
    const float* p1b    = (const float*)d_in[10];
    const float* p2w    = (const float*)d_in[11];
    const float* p2b    = (const float*)d_in[12];

    // workspace layout (byte offsets, all 16B-aligned)
    char* W = (char*)d_ws;
    float*  biasF = (float*)(W + 0);             // 692224*4 = 2,768,896
    ushort* Wc    = (ushort*)(W + 2768896);      // 32,768
    ushort* Wp1   = (ushort*)(W + 2801664);      //  8,192
    ushort* Wp2   = (ushort*)(W + 2809856);      //  8,192
    float*  Bc    = (float*) (W + 2818048);      //  1,024
    float*  tab   = (float*) (W + 2819072);      // 6084*4 = 24,336
    const size_t BASE2 = 2843648;
    const size_t BB = (size_t)BP * NP * 64 * 2;  // 6,815,744 per bf16 NP buffer
    ushort* Qb = (ushort*)(W + BASE2);
    ushort* Kb = (ushort*)(W + BASE2 + 1 * BB);
    ushort* Vb = (ushort*)(W + BASE2 + 2 * BB);
    ushort* XG = (ushort*)(W + BASE2 + 3 * BB);
    ushort* P1 = (ushort*)(W + BASE2 + 4 * BB);
    const size_t OB = (size_t)BP * 400 * 64 * 2; // 6,553,600 per bf16 contiguous buffer
    ushort* O1 = (ushort*)(W + BASE2 + 5 * BB);
    ushort* O2 = (ushort*)(W + BASE2 + 5 * BB + OB);
    float*  out = (float*)d_out;

    k_tab<<<24, 256, 0, stream>>>(pw1, pb1, pw2, pb2, tab);
    k_prep<<<2801, 256, 0, stream>>>(tab, qkv_w, qkv_b, grid_w, grid_b,
                                     p1w, p2w, biasF, Wc, Bc, Wp1, Wp2);
    k_conv<<<1600, 256, 0, stream>>>(x, Wc, Bc, Qb, Kb, Vb, XG);
    // attn1: q=XG, k=Kb(prescaled), v=Vb -> O1; proj1 -> P1 (bf16, NP-padded)
    k_attn_mfma<<<512, 512, 0, stream>>>(XG, Kb, Vb, biasF, O1);
    k_proj<<<400, 256, 0, stream>>>(O1, Wp1, p1b, P1);
    // attn2: q=Qb(prescaled), k=XG, v=P1 -> O2; fused proj2+unshuffle -> out (fp32)
    k_attn_mfma<<<512, 512, 0, stream>>>(Qb, XG, P1, biasF, O2);
    k_proj_out<<<320, 256, 0, stream>>>(O2, Wp2, p2b, out);
}